// Round 7
// baseline (20955.415 us; speedup 1.0000x reference)
//
#include <hip/hip_runtime.h>

#define N_UNITS 2048
#define N_IN 16
#define BATCH 64
#define T_STEPS 512
#define NBLK 128

typedef __attribute__((ext_vector_type(8))) short bf16x8;
typedef __attribute__((ext_vector_type(4))) float f32x4;
typedef __attribute__((ext_vector_type(4))) unsigned short u16x4;

// d_ws layout (bytes):
//  0        : Ap  [128 mtile][130 chunk][64 lane][8] bf16  (17,039,360 B)
//             chunks 0..63 = W_hi, 64..127 = W_lo, 128..129 = |inp| hi/hi/lo/0 block
//  17039360 : Bx  [512 t][4 nt][2 c2][64 lane][8] bf16     (4 MiB) x-term B-frags
//  21233664 : Br0 [4 nt][128 chunk][64 lane][8] bf16       (512 KiB) r̂ frags (hi|lo)
//  21757952 : Br1                                           (512 KiB)
//  22282240 : act [64 b][2048 u] f32                        (512 KiB, = output layout)
// barrier state lives in d_out[0..1] (overwritten by k_out at the end).
#define AP_OFF   0
#define BX_OFF   17039360
#define BR0_OFF  21233664
#define BR1_OFF  21757952
#define ACT_OFF  22282240

__device__ __forceinline__ unsigned short f2bf(float f) {
  unsigned int u = __float_as_uint(f);
  u += 0x7FFFu + ((u >> 16) & 1u);   // RNE
  return (unsigned short)(u >> 16);
}
__device__ __forceinline__ float bf2f(unsigned short h) {
  return __uint_as_float(((unsigned int)h) << 16);
}

// Pack A = [W_hi | W_lo | x-block] into MFMA fragment order.
// wave wid = mtile*130 + c; lane l: A[m][k], m = mtile*16+(l&15), k = c*32+(l>>4)*8+j.
__global__ __launch_bounds__(256) void k_packA(const float* __restrict__ Wd,
                                               const float* __restrict__ Wn,
                                               const float* __restrict__ sdale,
                                               const float* __restrict__ alphap,
                                               const float* __restrict__ inp,
                                               unsigned short* __restrict__ Ap) {
  int wid = blockIdx.x * 4 + (threadIdx.x >> 6);
  int l = threadIdx.x & 63;
  int mtile = wid / 130;
  int c = wid - mtile * 130;
  float a = fminf(fmaxf(alphap[0], 0.f), 1.f);  // Hardtanh(0,1)
  float bb = 1.f - a;
  int u = mtile * 16 + (l & 15);
  int kb = (l >> 4) * 8;
  unsigned short o[8];
  if (c < 128) {
    int k0 = (c & 63) * 32 + kb;
    bool lo = (c >= 64);
    const float* wd = Wd + (size_t)u * 2048 + k0;
    const float* wn = Wn + (size_t)u * 2048 + k0;
    const float* sd = sdale + k0;
#pragma unroll
    for (int j = 0; j < 8; ++j) {
      float v = a * fabsf(wd[j]) * sd[j] + bb * wn[j];  // Wsum[u][k]
      unsigned short h = f2bf(v);
      o[j] = lo ? f2bf(v - bf2f(h)) : h;
    }
  } else {
    int cw = c - 128;
#pragma unroll
    for (int j = 0; j < 8; ++j) {
      int kk = cw * 32 + kb + j;       // 0..63
      int sect = kk >> 4, i = kk & 15; // sect: 0 inp_hi,1 inp_hi,2 inp_lo,3 zero
      float v = fabsf(inp[i * 2048 + u]);
      unsigned short h = f2bf(v);
      o[j] = (sect == 3) ? (unsigned short)0
                         : (sect == 2 ? f2bf(v - bf2f(h)) : h);
    }
  }
  unsigned short* dst = Ap + ((size_t)wid * 64 + l) * 8;
  *(u16x4*)dst = u16x4{o[0], o[1], o[2], o[3]};
  *(u16x4*)(dst + 4) = u16x4{o[4], o[5], o[6], o[7]};
}

// Pack x-term B-frags for all t. wave wid = t*8 + nt*2 + c2.
// B[k][n]: n = nt*16+(l&15)=batch, kk = c2*32+(l>>4)*8+j; sect: 0 x_hi,1 x_lo,2 x_hi,3 0.
__global__ __launch_bounds__(256) void k_packBx(const float* __restrict__ inputs,
                                                unsigned short* __restrict__ Bx) {
  int wid = blockIdx.x * 4 + (threadIdx.x >> 6);
  int l = threadIdx.x & 63;
  int t = wid >> 3, r = wid & 7, nt = r >> 1, c2 = r & 1;
  int b = nt * 16 + (l & 15);
  int kb = (l >> 4) * 8;
  unsigned short o[8];
#pragma unroll
  for (int j = 0; j < 8; ++j) {
    int kk = c2 * 32 + kb + j;
    int sect = kk >> 4, i = kk & 15;
    float x = inputs[(size_t)b * 8192 + i * 512 + t];  // inputs[b][i][t]
    unsigned short h = f2bf(x);
    o[j] = (sect == 3) ? (unsigned short)0
                       : (sect == 1 ? f2bf(x - bf2f(h)) : h);
  }
  unsigned short* dst = Bx + ((size_t)wid * 64 + l) * 8;
  *(u16x4*)dst = u16x4{o[0], o[1], o[2], o[3]};
  *(u16x4*)(dst + 4) = u16x4{o[4], o[5], o[6], o[7]};
}

__global__ __launch_bounds__(256) void k_zero(float4* __restrict__ p,
                                              unsigned* __restrict__ bar) {
  p[blockIdx.x * 256 + threadIdx.x] = make_float4(0.f, 0.f, 0.f, 0.f);
  if (blockIdx.x == 0 && threadIdx.x == 0) { bar[0] = 0u; bar[1] = 0u; }
}

#define MFMA(A, B, C) __builtin_amdgcn_mfma_f32_16x16x32_bf16(A, B, C, 0, 0, 0)

// Persistent step loop. 128 WGs x 4 waves, all co-resident (1 WG/CU max).
// Per step: WG = 16 units x 64 batch; wave w owns K-quarter (chunks w*16..+15);
// 12 MFMAs per chunk over 4 acc chains (nt); x-block on waves 0,1; LDS
// cross-wave reduce; fused leak+noise update; r̂ written in B-frag layout.
// Grid barrier (sense-reversing, device-scope) between steps.
__global__ __launch_bounds__(256, 1) void k_persist(
    const unsigned short* __restrict__ Ap,
    unsigned short* __restrict__ Br0,
    unsigned short* __restrict__ Br1,
    const unsigned short* __restrict__ Bx,
    const float* __restrict__ noise,
    float* __restrict__ act,
    unsigned* __restrict__ bar) {
  const int tid = threadIdx.x;
  const int w = __builtin_amdgcn_readfirstlane(tid >> 6);
  const int l = tid & 63;
  const int u0 = blockIdx.x * 16;

  const unsigned short* Aw = Ap + ((size_t)blockIdx.x * 130) * 512 + l * 8;
  __shared__ float red[4][16][66];

  for (int t = 0; t < T_STEPS; ++t) {
    const unsigned short* Brc = (t & 1) ? Br1 : Br0;
    unsigned short* Brn = (t & 1) ? Br0 : Br1;
    const unsigned short* Bxt = Bx + (size_t)t * 4096;
    const float* noise_t = noise + (size_t)t * 131072;
    const unsigned short* Bl = Brc + l * 8;

    f32x4 acc0 = {0.f, 0.f, 0.f, 0.f}, acc1 = acc0, acc2 = acc0, acc3 = acc0;

    const int cbase = w * 16;
#pragma unroll 2
    for (int cc = 0; cc < 16; ++cc) {
      const int c = cbase + cc;
      bf16x8 ah = *(const bf16x8*)(Aw + (size_t)c * 512);
      bf16x8 al = *(const bf16x8*)(Aw + (size_t)(64 + c) * 512);
      bf16x8 bh0 = *(const bf16x8*)(Bl + (size_t)(0 * 128 + c) * 512);
      bf16x8 bh1 = *(const bf16x8*)(Bl + (size_t)(1 * 128 + c) * 512);
      bf16x8 bh2 = *(const bf16x8*)(Bl + (size_t)(2 * 128 + c) * 512);
      bf16x8 bh3 = *(const bf16x8*)(Bl + (size_t)(3 * 128 + c) * 512);
      bf16x8 bl0 = *(const bf16x8*)(Bl + (size_t)(0 * 128 + 64 + c) * 512);
      bf16x8 bl1 = *(const bf16x8*)(Bl + (size_t)(1 * 128 + 64 + c) * 512);
      bf16x8 bl2 = *(const bf16x8*)(Bl + (size_t)(2 * 128 + 64 + c) * 512);
      bf16x8 bl3 = *(const bf16x8*)(Bl + (size_t)(3 * 128 + 64 + c) * 512);
      acc0 = MFMA(ah, bh0, acc0);  // W_hi · r_hi
      acc1 = MFMA(ah, bh1, acc1);
      acc2 = MFMA(ah, bh2, acc2);
      acc3 = MFMA(ah, bh3, acc3);
      acc0 = MFMA(ah, bl0, acc0);  // W_hi · r_lo
      acc1 = MFMA(ah, bl1, acc1);
      acc2 = MFMA(ah, bl2, acc2);
      acc3 = MFMA(ah, bl3, acc3);
      acc0 = MFMA(al, bh0, acc0);  // W_lo · r_hi
      acc1 = MFMA(al, bh1, acc1);
      acc2 = MFMA(al, bh2, acc2);
      acc3 = MFMA(al, bh3, acc3);
    }
    if (w < 2) {  // x-term chunks (2 of them) on waves 0,1
      bf16x8 ax = *(const bf16x8*)(Aw + (size_t)(128 + w) * 512);
      bf16x8 bx0 = *(const bf16x8*)(Bxt + (size_t)(0 * 2 + w) * 512 + l * 8);
      bf16x8 bx1 = *(const bf16x8*)(Bxt + (size_t)(1 * 2 + w) * 512 + l * 8);
      bf16x8 bx2 = *(const bf16x8*)(Bxt + (size_t)(2 * 2 + w) * 512 + l * 8);
      bf16x8 bx3 = *(const bf16x8*)(Bxt + (size_t)(3 * 2 + w) * 512 + l * 8);
      acc0 = MFMA(ax, bx0, acc0);
      acc1 = MFMA(ax, bx1, acc1);
      acc2 = MFMA(ax, bx2, acc2);
      acc3 = MFMA(ax, bx3, acc3);
    }

    // update-phase global loads (issue early; latency hides under reduce)
    const int b = tid >> 2;
    const int ub = (tid & 3) * 4;
    const int ug = u0 + ub;
    const float4 nz = *(const float4*)(noise_t + (size_t)b * 2048 + ug);
    const float4 ao = *(const float4*)(act + (size_t)b * 2048 + ug);

    // cross-wave reduce: D[m][n]: m=(l>>4)*4+q, n=nt*16+(l&15)
    const int rl = l & 15, rh = l >> 4;
    __syncthreads();  // red safe to overwrite (prev step's readers done at barrier)
#pragma unroll
    for (int q = 0; q < 4; ++q) {
      red[w][rh * 4 + q][0 + rl] = acc0[q];
      red[w][rh * 4 + q][16 + rl] = acc1[q];
      red[w][rh * 4 + q][32 + rl] = acc2[q];
      red[w][rh * 4 + q][48 + rl] = acc3[q];
    }
    __syncthreads();

    float dr[4];
#pragma unroll
    for (int i = 0; i < 4; ++i)
      dr[i] = red[0][ub + i][b] + red[1][ub + i][b] +
              red[2][ub + i][b] + red[3][ub + i][b];

    float4 an;
    an.x = 0.8f * ao.x + 0.2f * dr[0] + nz.x;
    an.y = 0.8f * ao.y + 0.2f * dr[1] + nz.y;
    an.z = 0.8f * ao.z + 0.2f * dr[2] + nz.z;
    an.w = 0.8f * ao.w + 0.2f * dr[3] + nz.w;
    *(float4*)(act + (size_t)b * 2048 + ug) = an;

    // write r̂ = relu(an) hi/lo directly in B-frag layout for next step
    float rr[4] = {fmaxf(an.x, 0.f), fmaxf(an.y, 0.f),
                   fmaxf(an.z, 0.f), fmaxf(an.w, 0.f)};
    u16x4 hv, lv;
#pragma unroll
    for (int i = 0; i < 4; ++i) {
      unsigned short h = f2bf(rr[i]);
      hv[i] = h;
      lv[i] = f2bf(rr[i] - bf2f(h));
    }
    const int c = ug >> 5;                         // k-chunk (k = source unit)
    const int kk = ug & 31;
    const int lane_b = (b & 15) + 16 * (kk >> 3);
    const int j = kk & 7;                          // {0,4}, u16x4-aligned
    const int nt = b >> 4;
    unsigned short* dst = Brn + ((size_t)(nt * 128 + c) * 64 + lane_b) * 8 + j;
    *(u16x4*)dst = hv;
    *(u16x4*)(dst + 32768) = lv;                   // chunk c+64 (r_lo region)

    // ---- grid barrier (device scope, sense-reversing via generation) ----
    __syncthreads();
    if (tid == 0) {
      __threadfence();  // release this WG's Brn/act writes
      unsigned g = __hip_atomic_load(&bar[1], __ATOMIC_RELAXED,
                                     __HIP_MEMORY_SCOPE_AGENT);
      unsigned a = __hip_atomic_fetch_add(&bar[0], 1u, __ATOMIC_ACQ_REL,
                                          __HIP_MEMORY_SCOPE_AGENT);
      if (a == NBLK - 1) {
        __hip_atomic_store(&bar[0], 0u, __ATOMIC_RELAXED,
                           __HIP_MEMORY_SCOPE_AGENT);
        __hip_atomic_store(&bar[1], g + 1u, __ATOMIC_RELEASE,
                           __HIP_MEMORY_SCOPE_AGENT);
      } else {
        while (__hip_atomic_load(&bar[1], __ATOMIC_ACQUIRE,
                                 __HIP_MEMORY_SCOPE_AGENT) == g)
          __builtin_amdgcn_s_sleep(2);
      }
    }
    __syncthreads();
    __threadfence();  // all threads: invalidate L1 so next step sees peers' writes
  }
}

__global__ __launch_bounds__(256) void k_trans(const float4* __restrict__ act,
                                               float4* __restrict__ out) {
  int idx = blockIdx.x * 256 + threadIdx.x;  // act already [b][u] = output layout
  out[idx] = act[idx];
}

__global__ __launch_bounds__(256) void k_out(const float* __restrict__ act,
                                             const float* __restrict__ outw,
                                             float* __restrict__ out) {
  __shared__ float red[256];
  int b = blockIdx.x, tid = threadIdx.x;
  float p = 0.f;
  for (int u = tid; u < N_UNITS; u += 256)
    p = fmaf(act[b * N_UNITS + u], outw[u], p);
  red[tid] = p;
  __syncthreads();
  for (int s = 128; s > 0; s >>= 1) {
    if (tid < s) red[tid] += red[tid + s];
    __syncthreads();
  }
  if (tid == 0) out[b] = red[0];
}

extern "C" void kernel_launch(void* const* d_in, const int* in_sizes, int n_in,
                              void* d_out, int out_size, void* d_ws, size_t ws_size,
                              hipStream_t stream) {
  const float* inputs = (const float*)d_in[0];  // [64,16,512]
  const float* noise  = (const float*)d_in[1];  // [512,64,2048]
  const float* inp    = (const float*)d_in[2];  // [16,2048]
  const float* Wn     = (const float*)d_in[3];  // [2048,2048]
  const float* Wd     = (const float*)d_in[4];  // [2048,2048]
  const float* outw   = (const float*)d_in[5];  // [2048]
  const float* alpha  = (const float*)d_in[6];  // [1]
  const float* sdale  = (const float*)d_in[7];  // [2048]
  float* out = (float*)d_out;                   // [64] ++ [64*2048]

  char* ws = (char*)d_ws;
  unsigned short* Ap  = (unsigned short*)(ws + AP_OFF);
  unsigned short* Bx  = (unsigned short*)(ws + BX_OFF);
  unsigned short* Br0 = (unsigned short*)(ws + BR0_OFF);
  unsigned short* Br1 = (unsigned short*)(ws + BR1_OFF);
  float* act          = (float*)(ws + ACT_OFF);
  unsigned* bar       = (unsigned*)d_out;       // reused; k_out overwrites at end

  k_packA<<<4160, 256, 0, stream>>>(Wd, Wn, sdale, alpha, inp, Ap);
  k_packBx<<<1024, 256, 0, stream>>>(inputs, Bx);
  k_zero<<<384, 256, 0, stream>>>((float4*)(ws + BR0_OFF), bar);  // Br0|Br1|act

  k_persist<<<NBLK, 256, 0, stream>>>(Ap, Br0, Br1, Bx, noise, act, bar);

  k_trans<<<128, 256, 0, stream>>>((const float4*)act, (float4*)(out + BATCH));
  k_out<<<64, 256, 0, stream>>>(act, outw, out);
}